// Round 1
// baseline (1459.920 us; speedup 1.0000x reference)
//
#include <hip/hip_runtime.h>

#define N 8192
constexpr float BN_EPS = 1e-5f;

__device__ __forceinline__ void fma4(float4& c, float s, const float4& m) {
    c.x = fmaf(s, m.x, c.x);
    c.y = fmaf(s, m.y, c.y);
    c.z = fmaf(s, m.z, c.z);
    c.w = fmaf(s, m.w, c.w);
}

__device__ __forceinline__ float wave_reduce(float v) {
#pragma unroll
    for (int off = 32; off > 0; off >>= 1) v += __shfl_xor(v, off, 64);
    return v;
}

// alpha/delta of the affine form of BN: BN(z) = alpha*z + delta
__device__ __forceinline__ void bn_affine(const float* st, float cnt, float g, float b,
                                          float& alpha, float& delta) {
    float mean = st[0] / cnt;
    float var  = fmaxf(st[1] / cnt - mean * mean, 0.f);
    alpha = g / sqrtf(var + BN_EPS);
    delta = b - alpha * mean;
}

// ---------------------------------------------------------------------------
// Big pass: T = relu(A @ M + b), accumulating sum/sumsq of T into st[0],st[1].
// Two independent problem "halves" per launch (chains 1 & 2 share a launch).
// One wave processes 4 rows; lanes stride float4 across the 8192-wide row.
// ---------------------------------------------------------------------------
template <int K>
__global__ __launch_bounds__(256) void bigpass(
    const float* __restrict__ A0, const float* __restrict__ M0,
    const float* __restrict__ b0, float* __restrict__ T0, float* __restrict__ st0,
    const float* __restrict__ A1, const float* __restrict__ M1,
    const float* __restrict__ b1, float* __restrict__ T1, float* __restrict__ st1,
    int blocksPerHalf) {
    int bid = blockIdx.x;
    const float* A; const float* M; const float* bv; float* T; float* st;
    if (bid < blocksPerHalf) { A = A0; M = M0; bv = b0; T = T0; st = st0; }
    else { A = A1; M = M1; bv = b1; T = T1; st = st1; bid -= blocksPerHalf; }

    const int lane = threadIdx.x & 63;
    const int wv   = threadIdx.x >> 6;
    const int r0   = (bid * 4 + wv) * 4;  // 4 rows per wave

    const float4* Ar0 = (const float4*)(A + (size_t)(r0 + 0) * N);
    const float4* Ar1 = (const float4*)(A + (size_t)(r0 + 1) * N);
    const float4* Ar2 = (const float4*)(A + (size_t)(r0 + 2) * N);
    const float4* Ar3 = (const float4*)(A + (size_t)(r0 + 3) * N);
    const float4* M4  = (const float4*)M;

    if constexpr (K == 4) {
        float4 acc0 = {0, 0, 0, 0}, acc1 = {0, 0, 0, 0};
        float4 acc2 = {0, 0, 0, 0}, acc3 = {0, 0, 0, 0};
        for (int t = lane; t < N / 4; t += 64) {
            float4 m0 = M4[4 * t + 0], m1 = M4[4 * t + 1];
            float4 m2 = M4[4 * t + 2], m3 = M4[4 * t + 3];
            float4 a;
            a = Ar0[t]; fma4(acc0, a.x, m0); fma4(acc0, a.y, m1); fma4(acc0, a.z, m2); fma4(acc0, a.w, m3);
            a = Ar1[t]; fma4(acc1, a.x, m0); fma4(acc1, a.y, m1); fma4(acc1, a.z, m2); fma4(acc1, a.w, m3);
            a = Ar2[t]; fma4(acc2, a.x, m0); fma4(acc2, a.y, m1); fma4(acc2, a.z, m2); fma4(acc2, a.w, m3);
            a = Ar3[t]; fma4(acc3, a.x, m0); fma4(acc3, a.y, m1); fma4(acc3, a.z, m2); fma4(acc3, a.w, m3);
        }
        float r[4][4] = {{acc0.x, acc0.y, acc0.z, acc0.w},
                         {acc1.x, acc1.y, acc1.z, acc1.w},
                         {acc2.x, acc2.y, acc2.z, acc2.w},
                         {acc3.x, acc3.y, acc3.z, acc3.w}};
#pragma unroll
        for (int i = 0; i < 4; i++)
#pragma unroll
            for (int j = 0; j < 4; j++) r[i][j] = wave_reduce(r[i][j]);
        if (lane == 0) {
            float b4[4] = {bv[0], bv[1], bv[2], bv[3]};
            float s = 0.f, ss = 0.f;
#pragma unroll
            for (int i = 0; i < 4; i++) {
                float4 o;
                float* op = (float*)&o;
#pragma unroll
                for (int j = 0; j < 4; j++) {
                    float tv = fmaxf(r[i][j] + b4[j], 0.f);
                    op[j] = tv;
                    s += tv;
                    ss = fmaf(tv, tv, ss);
                }
                ((float4*)T)[r0 + i] = o;
            }
            atomicAdd(&st[0], s);
            atomicAdd(&st[1], ss);
        }
    } else {  // K == 1
        float c0 = 0.f, c1 = 0.f, c2 = 0.f, c3 = 0.f;
        for (int t = lane; t < N / 4; t += 64) {
            float4 m = M4[t];
            float4 a;
            a = Ar0[t]; c0 = fmaf(a.x, m.x, c0); c0 = fmaf(a.y, m.y, c0); c0 = fmaf(a.z, m.z, c0); c0 = fmaf(a.w, m.w, c0);
            a = Ar1[t]; c1 = fmaf(a.x, m.x, c1); c1 = fmaf(a.y, m.y, c1); c1 = fmaf(a.z, m.z, c1); c1 = fmaf(a.w, m.w, c1);
            a = Ar2[t]; c2 = fmaf(a.x, m.x, c2); c2 = fmaf(a.y, m.y, c2); c2 = fmaf(a.z, m.z, c2); c2 = fmaf(a.w, m.w, c2);
            a = Ar3[t]; c3 = fmaf(a.x, m.x, c3); c3 = fmaf(a.y, m.y, c3); c3 = fmaf(a.z, m.z, c3); c3 = fmaf(a.w, m.w, c3);
        }
        c0 = wave_reduce(c0); c1 = wave_reduce(c1);
        c2 = wave_reduce(c2); c3 = wave_reduce(c3);
        if (lane == 0) {
            float bb = bv[0];
            float t0 = fmaxf(c0 + bb, 0.f), t1v = fmaxf(c1 + bb, 0.f);
            float t2v = fmaxf(c2 + bb, 0.f), t3v = fmaxf(c3 + bb, 0.f);
            T[r0 + 0] = t0; T[r0 + 1] = t1v; T[r0 + 2] = t2v; T[r0 + 3] = t3v;
            float s  = t0 + t1v + t2v + t3v;
            float ss = fmaf(t0, t0, fmaf(t1v, t1v, fmaf(t2v, t2v, t3v * t3v)));
            atomicAdd(&st[0], s);
            atomicAdd(&st[1], ss);
        }
    }
}

// ---------------------------------------------------------------------------
// Small kernels
// ---------------------------------------------------------------------------
__global__ void zero_stats(float* stats) {
    if (threadIdx.x < 32) stats[threadIdx.x] = 0.f;
}

// M for blocks 1 & 3: Ma = x1 * w11, Mb = x2 * w21   (din = 1)
__global__ void prep1(const float* __restrict__ x, const float* __restrict__ w11,
                      const float* __restrict__ w21, float* __restrict__ Ma,
                      float* __restrict__ Mb) {
    int i = blockIdx.x * blockDim.x + threadIdx.x;
    if (i >= N) return;
    float x1 = x[i], x2 = x[N + i];
#pragma unroll
    for (int j = 0; j < 4; j++) {
        Ma[i * 4 + j] = x1 * w11[j];
        Mb[i * 4 + j] = x2 * w21[j];
    }
}

// M for blocks 2 & 4: fold BN affine of T1/T3 then @ w12/w22
__global__ void prep2(const float* __restrict__ stats, const float* __restrict__ gamma,
                      const float* __restrict__ beta, const float* __restrict__ T1,
                      const float* __restrict__ T3, const float* __restrict__ w12,
                      const float* __restrict__ w22, float* __restrict__ M2,
                      float* __restrict__ M4v) {
    int i = blockIdx.x * blockDim.x + threadIdx.x;
    if (i >= N) return;
    float g = *gamma, b = *beta;
    float al0, dl0, al1, dl1;
    bn_affine(stats + 0, (float)(N * 4), g, b, al0, dl0);
    bn_affine(stats + 2, (float)(N * 4), g, b, al1, dl1);
    float4 t1 = ((const float4*)T1)[i];
    float4 t3 = ((const float4*)T3)[i];
    float sw12 = w12[0] + w12[1] + w12[2] + w12[3];
    float sw22 = w22[0] + w22[1] + w22[2] + w22[3];
    M2[i]  = al0 * (t1.x * w12[0] + t1.y * w12[1] + t1.z * w12[2] + t1.w * w12[3]) + dl0 * sw12;
    M4v[i] = al1 * (t3.x * w22[0] + t3.y * w22[1] + t3.z * w22[2] + t3.w * w22[3]) + dl1 * sw22;
}

// M for block 5: F1_2 = relu(BN(T2)), F2_2 = relu(BN(T4)); Mc = F @ wc1
__global__ void prepc(const float* __restrict__ stats, const float* __restrict__ gamma,
                      const float* __restrict__ beta, const float* __restrict__ T2,
                      const float* __restrict__ T4, const float* __restrict__ wc1,
                      float* __restrict__ Mc) {
    int i = blockIdx.x * blockDim.x + threadIdx.x;
    if (i >= N) return;
    float g = *gamma, b = *beta;
    float al2, dl2, al3, dl3;
    bn_affine(stats + 4, (float)N, g, b, al2, dl2);
    bn_affine(stats + 6, (float)N, g, b, al3, dl3);
    float f1 = fmaxf(al2 * T2[i] + dl2, 0.f);
    float f2 = fmaxf(al3 * T4[i] + dl3, 0.f);
#pragma unroll
    for (int j = 0; j < 4; j++) Mc[i * 4 + j] = f1 * wc1[j] + f2 * wc1[4 + j];
}

// M for block 6
__global__ void prepf(const float* __restrict__ stats, const float* __restrict__ gamma,
                      const float* __restrict__ beta, const float* __restrict__ Tc,
                      const float* __restrict__ wc2, float* __restrict__ Mf) {
    int i = blockIdx.x * blockDim.x + threadIdx.x;
    if (i >= N) return;
    float g = *gamma, b = *beta;
    float al4, dl4;
    bn_affine(stats + 8, (float)(N * 4), g, b, al4, dl4);
    float4 tc = ((const float4*)Tc)[i];
    float swc2 = wc2[0] + wc2[1] + wc2[2] + wc2[3];
    Mf[i] = al4 * (tc.x * wc2[0] + tc.y * wc2[1] + tc.z * wc2[2] + tc.w * wc2[3]) + dl4 * swc2;
}

// out = relu(BN(Tf))
__global__ void finalout(const float* __restrict__ stats, const float* __restrict__ gamma,
                         const float* __restrict__ beta, const float* __restrict__ Tf,
                         float* __restrict__ out) {
    int i = blockIdx.x * blockDim.x + threadIdx.x;
    if (i >= N) return;
    float g = *gamma, b = *beta;
    float al5, dl5;
    bn_affine(stats + 10, (float)N, g, b, al5, dl5);
    out[i] = fmaxf(al5 * Tf[i] + dl5, 0.f);
}

// ---------------------------------------------------------------------------
extern "C" void kernel_launch(void* const* d_in, const int* in_sizes, int n_in,
                              void* d_out, int out_size, void* d_ws, size_t ws_size,
                              hipStream_t stream) {
    const float* x     = (const float*)d_in[0];
    const float* adj   = (const float*)d_in[1];
    const float* w11   = (const float*)d_in[2];
    const float* b11   = (const float*)d_in[3];
    const float* w12   = (const float*)d_in[4];
    const float* b12   = (const float*)d_in[5];
    const float* w21   = (const float*)d_in[6];
    const float* b21   = (const float*)d_in[7];
    const float* w22   = (const float*)d_in[8];
    const float* b22   = (const float*)d_in[9];
    const float* wc1   = (const float*)d_in[10];
    const float* bc1   = (const float*)d_in[11];
    const float* wc2   = (const float*)d_in[12];
    const float* bc2   = (const float*)d_in[13];
    const float* gamma = (const float*)d_in[14];
    const float* beta  = (const float*)d_in[15];
    float* out = (float*)d_out;

    const float* A1  = adj;
    const float* A2  = adj + (size_t)N * N;
    const float* A12 = adj + 2 * (size_t)N * N;

    float* wsf   = (float*)d_ws;
    float* stats = wsf;            // 32 floats: 6 slots x {sum, sumsq}
    float* Ma    = wsf + 32;       // [N,4]
    float* Mb    = Ma + N * 4;     // [N,4]
    float* T1    = Mb + N * 4;     // [N,4]
    float* T3    = T1 + N * 4;     // [N,4]
    float* M2    = T3 + N * 4;     // [N]
    float* M4v   = M2 + N;         // [N]
    float* T2    = M4v + N;        // [N]
    float* T4    = T2 + N;         // [N]
    float* Mc    = T4 + N;         // [N,4]
    float* Tc    = Mc + N * 4;     // [N,4]
    float* Mf    = Tc + N * 4;     // [N]
    float* Tf    = Mf + N;         // [N]

    dim3 blk(256);
    dim3 gsmall((N + 255) / 256);
    const int BPH = N / 16;  // 512 blocks per adjacency (16 rows/block)

    zero_stats<<<1, 32, 0, stream>>>(stats);
    prep1<<<gsmall, blk, 0, stream>>>(x, w11, w21, Ma, Mb);

    // blocks 1 & 3 (A1, A2) — 512 MB HBM
    bigpass<4><<<dim3(2 * BPH), blk, 0, stream>>>(A1, Ma, b11, T1, stats + 0,
                                                  A2, Mb, b21, T3, stats + 2, BPH);
    prep2<<<gsmall, blk, 0, stream>>>(stats, gamma, beta, T1, T3, w12, w22, M2, M4v);

    // blocks 2 & 4 — 512 MB HBM
    bigpass<1><<<dim3(2 * BPH), blk, 0, stream>>>(A1, M2, b12, T2, stats + 4,
                                                  A2, M4v, b22, T4, stats + 6, BPH);
    prepc<<<gsmall, blk, 0, stream>>>(stats, gamma, beta, T2, T4, wc1, Mc);

    // block 5 (A12) — 256 MB HBM
    bigpass<4><<<dim3(BPH), blk, 0, stream>>>(A12, Mc, bc1, Tc, stats + 8,
                                              A12, Mc, bc1, Tc, stats + 8, BPH);
    prepf<<<gsmall, blk, 0, stream>>>(stats, gamma, beta, Tc, wc2, Mf);

    // block 6 (A12) — 256 MB HBM
    bigpass<1><<<dim3(BPH), blk, 0, stream>>>(A12, Mf, bc2, Tf, stats + 10,
                                              A12, Mf, bc2, Tf, stats + 10, BPH);
    finalout<<<gsmall, blk, 0, stream>>>(stats, gamma, beta, Tf, out);
}

// Round 2
// 1187.916 us; speedup vs baseline: 1.2290x; 1.2290x over previous
//
#include <hip/hip_runtime.h>

#define N 8192
constexpr float BN_EPS = 1e-5f;

__device__ __forceinline__ float wave_reduce(float v) {
#pragma unroll
    for (int off = 32; off > 0; off >>= 1) v += __shfl_xor(v, off, 64);
    return v;
}

__device__ __forceinline__ float dot4acc(float c, const float4 a, const float4 m) {
    c = fmaf(a.x, m.x, c);
    c = fmaf(a.y, m.y, c);
    c = fmaf(a.z, m.z, c);
    c = fmaf(a.w, m.w, c);
    return c;
}

// alpha/delta of the affine form of BN: BN(z) = alpha*z + delta
__device__ __forceinline__ void bn_affine(const float* st, float cnt, float g, float b,
                                          float& alpha, float& delta) {
    float mean = st[0] / cnt;
    float var  = fmaxf(st[1] / cnt - mean * mean, 0.f);
    alpha = g / sqrtf(var + BN_EPS);
    delta = b - alpha * mean;
}

// ---------------------------------------------------------------------------
// Big pass: T = relu(A @ M + b), accumulating sum/sumsq of T into st[0],st[1].
// Two independent problem halves per launch. One wave = 4 rows, lanes stride
// float4 across the row. Staggered start chunk per wave (HBM channel spread);
// M stored transposed [K][N] so all M loads are coalesced; REV flips block->
// row mapping so re-read passes start on L3-resident rows.
// ---------------------------------------------------------------------------
template <int K, int REV>
__global__ __launch_bounds__(256) void bigpass(
    const float* __restrict__ A0, const float* __restrict__ M0,
    const float* __restrict__ b0, float* __restrict__ T0, float* __restrict__ st0,
    const float* __restrict__ A1, const float* __restrict__ M1,
    const float* __restrict__ b1, float* __restrict__ T1, float* __restrict__ st1,
    int blocksPerHalf) {
    int bid = blockIdx.x;
    const float* A; const float* M; const float* bv; float* T; float* st;
    if (bid < blocksPerHalf) { A = A0; M = M0; bv = b0; T = T0; st = st0; }
    else { A = A1; M = M1; bv = b1; T = T1; st = st1; bid -= blocksPerHalf; }
    if (REV) bid = blocksPerHalf - 1 - bid;

    const int lane = threadIdx.x & 63;
    const int wv   = threadIdx.x >> 6;
    const int r0   = (bid * 4 + wv) * 4;  // 4 rows per wave
    // stagger: distinct 1-KB start chunk per wave so concurrent addresses
    // cover the full 32-KB row period -> all HBM channels stay busy
    const int sgg  = (blockIdx.x * 4 + wv) & 31;

    const float4* Ar0 = (const float4*)(A + (size_t)(r0 + 0) * N);
    const float4* Ar1 = (const float4*)(A + (size_t)(r0 + 1) * N);
    const float4* Ar2 = (const float4*)(A + (size_t)(r0 + 2) * N);
    const float4* Ar3 = (const float4*)(A + (size_t)(r0 + 3) * N);

    __shared__ float sred[2][4];
    float s_acc = 0.f, ss_acc = 0.f;

    if constexpr (K == 4) {
        const float4* Mt0 = (const float4*)(M + 0 * N);
        const float4* Mt1 = (const float4*)(M + 1 * N);
        const float4* Mt2 = (const float4*)(M + 2 * N);
        const float4* Mt3 = (const float4*)(M + 3 * N);
        float c[4][4] = {{0.f}};
        for (int i = 0; i < 32; ++i) {
            const int t = (((i + sgg) & 31) << 6) + lane;
            float4 m[4] = {Mt0[t], Mt1[t], Mt2[t], Mt3[t]};
            float4 a[4] = {Ar0[t], Ar1[t], Ar2[t], Ar3[t]};
#pragma unroll
            for (int r = 0; r < 4; r++)
#pragma unroll
                for (int j = 0; j < 4; j++) c[r][j] = dot4acc(c[r][j], a[r], m[j]);
        }
#pragma unroll
        for (int r = 0; r < 4; r++)
#pragma unroll
            for (int j = 0; j < 4; j++) c[r][j] = wave_reduce(c[r][j]);
        if (lane == 0) {
            float b4[4] = {bv[0], bv[1], bv[2], bv[3]};
#pragma unroll
            for (int r = 0; r < 4; r++) {
                float4 o;
                float* op = (float*)&o;
#pragma unroll
                for (int j = 0; j < 4; j++) {
                    float tv = fmaxf(c[r][j] + b4[j], 0.f);
                    op[j] = tv;
                    s_acc += tv;
                    ss_acc = fmaf(tv, tv, ss_acc);
                }
                ((float4*)T)[r0 + r] = o;
            }
        }
    } else {  // K == 1
        const float4* M4 = (const float4*)M;
        float c0 = 0.f, c1 = 0.f, c2 = 0.f, c3 = 0.f;
        for (int i = 0; i < 32; ++i) {
            const int t = (((i + sgg) & 31) << 6) + lane;
            float4 m = M4[t];
            c0 = dot4acc(c0, Ar0[t], m);
            c1 = dot4acc(c1, Ar1[t], m);
            c2 = dot4acc(c2, Ar2[t], m);
            c3 = dot4acc(c3, Ar3[t], m);
        }
        c0 = wave_reduce(c0); c1 = wave_reduce(c1);
        c2 = wave_reduce(c2); c3 = wave_reduce(c3);
        if (lane == 0) {
            float bb = bv[0];
            float t0 = fmaxf(c0 + bb, 0.f), t1 = fmaxf(c1 + bb, 0.f);
            float t2 = fmaxf(c2 + bb, 0.f), t3 = fmaxf(c3 + bb, 0.f);
            T[r0 + 0] = t0; T[r0 + 1] = t1; T[r0 + 2] = t2; T[r0 + 3] = t3;
            s_acc  = t0 + t1 + t2 + t3;
            ss_acc = fmaf(t0, t0, fmaf(t1, t1, fmaf(t2, t2, t3 * t3)));
        }
    }

    // block-level stats reduction: 1 atomic pair per block instead of per wave
    if (lane == 0) { sred[0][wv] = s_acc; sred[1][wv] = ss_acc; }
    __syncthreads();
    if (threadIdx.x == 0) {
        float S  = sred[0][0] + sred[0][1] + sred[0][2] + sred[0][3];
        float SS = sred[1][0] + sred[1][1] + sred[1][2] + sred[1][3];
        atomicAdd(&st[0], S);
        atomicAdd(&st[1], SS);
    }
}

// ---------------------------------------------------------------------------
// Small kernels
// ---------------------------------------------------------------------------
__global__ void zero_stats(float* stats) {
    if (threadIdx.x < 32) stats[threadIdx.x] = 0.f;
}

// M (transposed [4][N]) for blocks 1 & 3: Ma = x1 * w11, Mb = x2 * w21
__global__ void prep1(const float* __restrict__ x, const float* __restrict__ w11,
                      const float* __restrict__ w21, float* __restrict__ Ma,
                      float* __restrict__ Mb) {
    int i = blockIdx.x * blockDim.x + threadIdx.x;
    if (i >= N) return;
    float x1 = x[i], x2 = x[N + i];
#pragma unroll
    for (int j = 0; j < 4; j++) {
        Ma[j * N + i] = x1 * w11[j];
        Mb[j * N + i] = x2 * w21[j];
    }
}

// M for blocks 2 & 4 (vectors): fold BN affine of T1/T3 then @ w12/w22
__global__ void prep2(const float* __restrict__ stats, const float* __restrict__ gamma,
                      const float* __restrict__ beta, const float* __restrict__ T1,
                      const float* __restrict__ T3, const float* __restrict__ w12,
                      const float* __restrict__ w22, float* __restrict__ M2,
                      float* __restrict__ M4v) {
    int i = blockIdx.x * blockDim.x + threadIdx.x;
    if (i >= N) return;
    float g = *gamma, b = *beta;
    float al0, dl0, al1, dl1;
    bn_affine(stats + 0, (float)(N * 4), g, b, al0, dl0);
    bn_affine(stats + 2, (float)(N * 4), g, b, al1, dl1);
    float4 t1 = ((const float4*)T1)[i];
    float4 t3 = ((const float4*)T3)[i];
    float sw12 = w12[0] + w12[1] + w12[2] + w12[3];
    float sw22 = w22[0] + w22[1] + w22[2] + w22[3];
    M2[i]  = al0 * (t1.x * w12[0] + t1.y * w12[1] + t1.z * w12[2] + t1.w * w12[3]) + dl0 * sw12;
    M4v[i] = al1 * (t3.x * w22[0] + t3.y * w22[1] + t3.z * w22[2] + t3.w * w22[3]) + dl1 * sw22;
}

// M (transposed [4][N]) for block 5
__global__ void prepc(const float* __restrict__ stats, const float* __restrict__ gamma,
                      const float* __restrict__ beta, const float* __restrict__ T2,
                      const float* __restrict__ T4, const float* __restrict__ wc1,
                      float* __restrict__ Mc) {
    int i = blockIdx.x * blockDim.x + threadIdx.x;
    if (i >= N) return;
    float g = *gamma, b = *beta;
    float al2, dl2, al3, dl3;
    bn_affine(stats + 4, (float)N, g, b, al2, dl2);
    bn_affine(stats + 6, (float)N, g, b, al3, dl3);
    float f1 = fmaxf(al2 * T2[i] + dl2, 0.f);
    float f2 = fmaxf(al3 * T4[i] + dl3, 0.f);
#pragma unroll
    for (int j = 0; j < 4; j++) Mc[j * N + i] = f1 * wc1[j] + f2 * wc1[4 + j];
}

// M for block 6 (vector)
__global__ void prepf(const float* __restrict__ stats, const float* __restrict__ gamma,
                      const float* __restrict__ beta, const float* __restrict__ Tc,
                      const float* __restrict__ wc2, float* __restrict__ Mf) {
    int i = blockIdx.x * blockDim.x + threadIdx.x;
    if (i >= N) return;
    float g = *gamma, b = *beta;
    float al4, dl4;
    bn_affine(stats + 8, (float)(N * 4), g, b, al4, dl4);
    float4 tc = ((const float4*)Tc)[i];
    float swc2 = wc2[0] + wc2[1] + wc2[2] + wc2[3];
    Mf[i] = al4 * (tc.x * wc2[0] + tc.y * wc2[1] + tc.z * wc2[2] + tc.w * wc2[3]) + dl4 * swc2;
}

// out = relu(BN(Tf))
__global__ void finalout(const float* __restrict__ stats, const float* __restrict__ gamma,
                         const float* __restrict__ beta, const float* __restrict__ Tf,
                         float* __restrict__ out) {
    int i = blockIdx.x * blockDim.x + threadIdx.x;
    if (i >= N) return;
    float g = *gamma, b = *beta;
    float al5, dl5;
    bn_affine(stats + 10, (float)N, g, b, al5, dl5);
    out[i] = fmaxf(al5 * Tf[i] + dl5, 0.f);
}

// ---------------------------------------------------------------------------
extern "C" void kernel_launch(void* const* d_in, const int* in_sizes, int n_in,
                              void* d_out, int out_size, void* d_ws, size_t ws_size,
                              hipStream_t stream) {
    const float* x     = (const float*)d_in[0];
    const float* adj   = (const float*)d_in[1];
    const float* w11   = (const float*)d_in[2];
    const float* b11   = (const float*)d_in[3];
    const float* w12   = (const float*)d_in[4];
    const float* b12   = (const float*)d_in[5];
    const float* w21   = (const float*)d_in[6];
    const float* b21   = (const float*)d_in[7];
    const float* w22   = (const float*)d_in[8];
    const float* b22   = (const float*)d_in[9];
    const float* wc1   = (const float*)d_in[10];
    const float* bc1   = (const float*)d_in[11];
    const float* wc2   = (const float*)d_in[12];
    const float* bc2   = (const float*)d_in[13];
    const float* gamma = (const float*)d_in[14];
    const float* beta  = (const float*)d_in[15];
    float* out = (float*)d_out;

    const float* A1  = adj;
    const float* A2  = adj + (size_t)N * N;
    const float* A12 = adj + 2 * (size_t)N * N;

    float* wsf   = (float*)d_ws;
    float* stats = wsf;            // 32 floats: 6 slots x {sum, sumsq}
    float* Ma    = wsf + 32;       // [4,N] transposed
    float* Mb    = Ma + N * 4;     // [4,N]
    float* T1    = Mb + N * 4;     // [N,4] row-major
    float* T3    = T1 + N * 4;     // [N,4]
    float* M2    = T3 + N * 4;     // [N]
    float* M4v   = M2 + N;         // [N]
    float* T2    = M4v + N;        // [N]
    float* T4    = T2 + N;         // [N]
    float* Mc    = T4 + N;         // [4,N]
    float* Tc    = Mc + N * 4;     // [N,4]
    float* Mf    = Tc + N * 4;     // [N]
    float* Tf    = Mf + N;         // [N]

    dim3 blk(256);
    dim3 gsmall((N + 255) / 256);
    const int BPH = N / 16;  // 512 blocks per adjacency (16 rows/block)

    zero_stats<<<1, 32, 0, stream>>>(stats);
    prep1<<<gsmall, blk, 0, stream>>>(x, w11, w21, Ma, Mb);

    // blocks 1 & 3 (A1, A2) — 512 MB HBM, first touch
    bigpass<4, 0><<<dim3(2 * BPH), blk, 0, stream>>>(A1, Ma, b11, T1, stats + 0,
                                                     A2, Mb, b21, T3, stats + 2, BPH);
    prep2<<<gsmall, blk, 0, stream>>>(stats, gamma, beta, T1, T3, w12, w22, M2, M4v);

    // blocks 2 & 4 — re-read of A1/A2: reversed order to hit L3-resident tail
    bigpass<1, 1><<<dim3(2 * BPH), blk, 0, stream>>>(A1, M2, b12, T2, stats + 4,
                                                     A2, M4v, b22, T4, stats + 6, BPH);
    prepc<<<gsmall, blk, 0, stream>>>(stats, gamma, beta, T2, T4, wc1, Mc);

    // block 5 (A12) — 256 MB, first touch
    bigpass<4, 0><<<dim3(BPH), blk, 0, stream>>>(A12, Mc, bc1, Tc, stats + 8,
                                                 A12, Mc, bc1, Tc, stats + 8, BPH);
    prepf<<<gsmall, blk, 0, stream>>>(stats, gamma, beta, Tc, wc2, Mf);

    // block 6 (A12) — re-read: reversed order, A12 ~= L3 size -> big hit rate
    bigpass<1, 1><<<dim3(BPH), blk, 0, stream>>>(A12, Mf, bc2, Tf, stats + 10,
                                                 A12, Mf, bc2, Tf, stats + 10, BPH);
    finalout<<<gsmall, blk, 0, stream>>>(stats, gamma, beta, Tf, out);
}